// Round 12
// baseline (13624.608 us; speedup 1.0000x reference)
//
#include <hip/hip_runtime.h>
#include <hip/hip_bf16.h>
#include <hip/hip_cooperative_groups.h>

namespace cg = cooperative_groups;

// Decoder: attention + LSTMCell + proj + vocab scoring.
// B=32, S=512, T=64, DENC=DHID=1024, DEMB=512, V=32000.
// Precision: recurrent state f32; GEMMs split-bf16 (hi/lo, 3 MFMA chains).
// R12: persistent cooperative kernel for the whole T-loop (kills ~20us/step of
//      launch gaps; 3 grid.sync()/step). Phases = R9's kernels verbatim.
//      X and H double-buffered by step parity so every phase is R/W disjoint.
//      k_out reverted to the measured-best R4 config (339us).

#define B_   32
#define S_   512
#define T_   64
#define DENC 1024
#define DHID 1024
#define DEMB 512
#define V_   32000
#define KX   2560   // X row: [ctx 1024 | h 1024 | e 512]
#define KP   2048   // proj K: [ctx | h]
#define NCH  32     // attention s-chunks per batch (16 rows each)

using short8 = __attribute__((ext_vector_type(8))) short;
using f32x4  = __attribute__((ext_vector_type(4))) float;
typedef __hip_bfloat16 bf16;

__device__ __forceinline__ float sigmoidf_(float x) { return 1.0f / (1.0f + expf(-x)); }
__device__ __forceinline__ bf16 bhi(float x) { return __float2bfloat16(x); }
__device__ __forceinline__ bf16 blo(float x) {
    return __float2bfloat16(x - __bfloat162float(__float2bfloat16(x)));
}

#define MFMA(a, b, c) __builtin_amdgcn_mfma_f32_16x16x32_bf16((a), (b), (c), 0, 0, 0)
#define DOT4(a, b) fmaf((a).x, (b).x, fmaf((a).y, (b).y, fmaf((a).z, (b).z, (a).w * (b).w)))

// ---------------- setup kernels ----------------

__global__ void k_build_wg(const float* __restrict__ W_ih, const float* __restrict__ W_hh,
                           const float* __restrict__ b_ih, const float* __restrict__ b_hh,
                           bf16* __restrict__ Wh, bf16* __restrict__ Wl, float* __restrict__ bias) {
    int jp = blockIdx.x;            // 0..4095, j' = d*4 + gate
    int g = jp & 3, d = jp >> 2;
    int j = g * 1024 + d;           // source row (torch gate order i,f,g,o)
    const float* wi = W_ih + (size_t)j * 1536;
    const float* wh = W_hh + (size_t)j * 1024;
    bf16* dh = Wh + (size_t)jp * KX;
    bf16* dl = Wl + (size_t)jp * KX;
    for (int i = threadIdx.x; i < 1024; i += 256) { float v = wi[i];      dh[i] = bhi(v);        dl[i] = blo(v); }
    for (int i = threadIdx.x; i < 1024; i += 256) { float v = wh[i];      dh[1024+i] = bhi(v);   dl[1024+i] = blo(v); }
    for (int i = threadIdx.x; i < 512;  i += 256) { float v = wi[1024+i]; dh[2048+i] = bhi(v);   dl[2048+i] = blo(v); }
    if (threadIdx.x == 0) bias[jp] = b_ih[j] + b_hh[j];
}

__global__ void k_cvt(const float* __restrict__ src, bf16* __restrict__ dst, long n) {
    long i = (long)blockIdx.x * blockDim.x + threadIdx.x;
    long stride = (long)gridDim.x * blockDim.x;
    for (; i < n; i += stride) dst[i] = __float2bfloat16(src[i]);
}

__global__ void k_cvt_split(const float* __restrict__ src, bf16* __restrict__ dh,
                            bf16* __restrict__ dl, long n) {
    long i = (long)blockIdx.x * blockDim.x + threadIdx.x;
    long stride = (long)gridDim.x * blockDim.x;
    for (; i < n; i += stride) { float v = src[i]; dh[i] = bhi(v); dl[i] = blo(v); }
}

__global__ void k_init(const float* __restrict__ h0, const float* __restrict__ c0,
                       const float* __restrict__ emb0,
                       float* __restrict__ h, float* __restrict__ c,
                       bf16* __restrict__ H0h, bf16* __restrict__ H0l,
                       bf16* __restrict__ X0h, bf16* __restrict__ X0l) {
    int b = blockIdx.x;   // 32 blocks
    for (int d = threadIdx.x; d < 1024; d += 256) {
        float v = h0[d];
        h[b * 1024 + d] = v;
        c[b * 1024 + d] = c0[d];
        H0h[b * 1024 + d] = bhi(v);
        H0l[b * 1024 + d] = blo(v);
    }
    for (int d = threadIdx.x; d < 512; d += 256) {
        float v = emb0[d];
        X0h[(size_t)b * KX + 2048 + d] = bhi(v);
        X0l[(size_t)b * KX + 2048 + d] = blo(v);
    }
}

// ---------------- phase device functions ----------------

// attention partials for one (b, ch) unit; block-wide (256 thr).
__device__ __forceinline__ void att_unit(
    const float* __restrict__ enc, const float* __restrict__ mask,
    const float* __restrict__ h,
    float* __restrict__ pml, float* __restrict__ pctx, int b, int ch)
{
    __shared__ float lctx[4][1024];
    __shared__ float lm[4], ll[4];
    int tid = threadIdx.x, wave = tid >> 6, lane = tid & 63;

    float4 hreg[4];
    const float4* h4p = (const float4*)(h + b * 1024);
#pragma unroll
    for (int j = 0; j < 4; ++j) hreg[j] = h4p[j * 64 + lane];

    const float* encb = enc + (size_t)b * S_ * DENC;
    int srow0 = ch * 16 + wave * 4;
    const float4* r0 = (const float4*)(encb + (size_t)(srow0 + 0) * DENC);
    const float4* r1 = (const float4*)(encb + (size_t)(srow0 + 1) * DENC);
    const float4* r2 = (const float4*)(encb + (size_t)(srow0 + 2) * DENC);
    const float4* r3 = (const float4*)(encb + (size_t)(srow0 + 3) * DENC);
    float4 e00 = r0[lane], e01 = r0[64+lane], e02 = r0[128+lane], e03 = r0[192+lane];
    float4 e10 = r1[lane], e11 = r1[64+lane], e12 = r1[128+lane], e13 = r1[192+lane];
    float4 e20 = r2[lane], e21 = r2[64+lane], e22 = r2[128+lane], e23 = r2[192+lane];
    float4 e30 = r3[lane], e31 = r3[64+lane], e32 = r3[128+lane], e33 = r3[192+lane];

    float d0 = DOT4(e00,hreg[0]) + DOT4(e01,hreg[1]) + DOT4(e02,hreg[2]) + DOT4(e03,hreg[3]);
    float d1 = DOT4(e10,hreg[0]) + DOT4(e11,hreg[1]) + DOT4(e12,hreg[2]) + DOT4(e13,hreg[3]);
    float d2 = DOT4(e20,hreg[0]) + DOT4(e21,hreg[1]) + DOT4(e22,hreg[2]) + DOT4(e23,hreg[3]);
    float d3 = DOT4(e30,hreg[0]) + DOT4(e31,hreg[1]) + DOT4(e32,hreg[2]) + DOT4(e33,hreg[3]);
#pragma unroll
    for (int off = 32; off; off >>= 1) {
        d0 += __shfl_xor(d0, off, 64);
        d1 += __shfl_xor(d1, off, 64);
        d2 += __shfl_xor(d2, off, 64);
        d3 += __shfl_xor(d3, off, 64);
    }
    float sc0 = d0 - (1.0f - mask[b * S_ + srow0 + 0]) * 1e20f;
    float sc1 = d1 - (1.0f - mask[b * S_ + srow0 + 1]) * 1e20f;
    float sc2 = d2 - (1.0f - mask[b * S_ + srow0 + 2]) * 1e20f;
    float sc3 = d3 - (1.0f - mask[b * S_ + srow0 + 3]) * 1e20f;
    float mw = fmaxf(fmaxf(sc0, sc1), fmaxf(sc2, sc3));
    float w0 = expf(sc0 - mw), w1 = expf(sc1 - mw);
    float w2 = expf(sc2 - mw), w3 = expf(sc3 - mw);
    float lw = w0 + w1 + w2 + w3;
    float4 c0, c1, c2, c3;
    c0.x = w0*e00.x + w1*e10.x + w2*e20.x + w3*e30.x;
    c0.y = w0*e00.y + w1*e10.y + w2*e20.y + w3*e30.y;
    c0.z = w0*e00.z + w1*e10.z + w2*e20.z + w3*e30.z;
    c0.w = w0*e00.w + w1*e10.w + w2*e20.w + w3*e30.w;
    c1.x = w0*e01.x + w1*e11.x + w2*e21.x + w3*e31.x;
    c1.y = w0*e01.y + w1*e11.y + w2*e21.y + w3*e31.y;
    c1.z = w0*e01.z + w1*e11.z + w2*e21.z + w3*e31.z;
    c1.w = w0*e01.w + w1*e11.w + w2*e21.w + w3*e31.w;
    c2.x = w0*e02.x + w1*e12.x + w2*e22.x + w3*e32.x;
    c2.y = w0*e02.y + w1*e12.y + w2*e22.y + w3*e32.y;
    c2.z = w0*e02.z + w1*e12.z + w2*e22.z + w3*e32.z;
    c2.w = w0*e02.w + w1*e12.w + w2*e22.w + w3*e32.w;
    c3.x = w0*e03.x + w1*e13.x + w2*e23.x + w3*e33.x;
    c3.y = w0*e03.y + w1*e13.y + w2*e23.y + w3*e33.y;
    c3.z = w0*e03.z + w1*e13.z + w2*e23.z + w3*e33.z;
    c3.w = w0*e03.w + w1*e13.w + w2*e23.w + w3*e33.w;

    ((float4*)lctx[wave])[0 * 64 + lane] = c0;
    ((float4*)lctx[wave])[1 * 64 + lane] = c1;
    ((float4*)lctx[wave])[2 * 64 + lane] = c2;
    ((float4*)lctx[wave])[3 * 64 + lane] = c3;
    if (lane == 0) { lm[wave] = mw; ll[wave] = lw; }
    __syncthreads();

    float mb_ = fmaxf(fmaxf(lm[0], lm[1]), fmaxf(lm[2], lm[3]));
    float q0 = expf(lm[0] - mb_), q1 = expf(lm[1] - mb_);
    float q2 = expf(lm[2] - mb_), q3 = expf(lm[3] - mb_);
    float lb = ll[0] * q0 + ll[1] * q1 + ll[2] * q2 + ll[3] * q3;
    float4 a0 = ((float4*)lctx[0])[tid], a1 = ((float4*)lctx[1])[tid];
    float4 a2 = ((float4*)lctx[2])[tid], a3 = ((float4*)lctx[3])[tid];
    float4 v;
    v.x = a0.x * q0 + a1.x * q1 + a2.x * q2 + a3.x * q3;
    v.y = a0.y * q0 + a1.y * q1 + a2.y * q2 + a3.y * q3;
    v.z = a0.z * q0 + a1.z * q1 + a2.z * q2 + a3.z * q3;
    v.w = a0.w * q0 + a1.w * q1 + a2.w * q2 + a3.w * q3;
    int pi = b * NCH + ch;
    ((float4*)(pctx + (size_t)pi * 1024))[tid] = v;
    if (tid == 0) { pml[pi * 2] = mb_; pml[pi * 2 + 1] = lb; }
    __syncthreads();   // lctx reused by next unit
}

// combine partials -> Xc.ctx (split bf16), copy Ht -> Xc.h. One block per b.
__device__ __forceinline__ void comb_fn(
    const float* __restrict__ pml, const float* __restrict__ pctx,
    const bf16* __restrict__ Hth, const bf16* __restrict__ Htl,
    bf16* __restrict__ Xch, bf16* __restrict__ Xcl, int b)
{
    __shared__ float sml[NCH * 2];
    __shared__ float wch[NCH];
    int tid = threadIdx.x;
    if (tid < NCH * 2) sml[tid] = pml[b * NCH * 2 + tid];
    __syncthreads();
    float mf = -3.0e38f;
#pragma unroll
    for (int c = 0; c < NCH; ++c) mf = fmaxf(mf, sml[2 * c]);
    float lt = 0.f;
#pragma unroll
    for (int c = 0; c < NCH; ++c) lt += sml[2 * c + 1] * expf(sml[2 * c] - mf);
    if (tid < NCH) wch[tid] = expf(sml[2 * tid] - mf);
    __syncthreads();
    float inv = 1.0f / lt;
    const float4* base = (const float4*)(pctx + (size_t)b * NCH * 1024) + tid;
    float4 sacc = {0, 0, 0, 0};
#pragma unroll 8
    for (int c = 0; c < NCH; ++c) {
        float wc = wch[c];
        float4 p = base[c * 256];
        sacc.x = fmaf(wc, p.x, sacc.x); sacc.y = fmaf(wc, p.y, sacc.y);
        sacc.z = fmaf(wc, p.z, sacc.z); sacc.w = fmaf(wc, p.w, sacc.w);
    }
    sacc.x *= inv; sacc.y *= inv; sacc.z *= inv; sacc.w *= inv;
    size_t xi = (size_t)b * KX + tid * 4;
    Xch[xi + 0] = bhi(sacc.x); Xcl[xi + 0] = blo(sacc.x);
    Xch[xi + 1] = bhi(sacc.y); Xcl[xi + 1] = blo(sacc.y);
    Xch[xi + 2] = bhi(sacc.z); Xcl[xi + 2] = blo(sacc.z);
    Xch[xi + 3] = bhi(sacc.w); Xcl[xi + 3] = blo(sacc.w);
    ((unsigned long long*)(Xch + (size_t)b * KX + 1024))[tid] =
        ((const unsigned long long*)(Hth + (size_t)b * 1024))[tid];
    ((unsigned long long*)(Xcl + (size_t)b * KX + 1024))[tid] =
        ((const unsigned long long*)(Htl + (size_t)b * 1024))[tid];
    __syncthreads();
}

// proj for step tp: p = [ctx_tp | h_{tp+1}] @ PW^T + pb; gathers e_{tp+1} into Xe.
// One block per 16-col group (nbBlk 0..31).
__device__ __forceinline__ void proj_fn(
    const bf16* __restrict__ Xph, const bf16* __restrict__ Xpl,   // ctx_tp source
    const bf16* __restrict__ Hph, const bf16* __restrict__ Hpl,   // h_{tp+1} source
    const bf16* __restrict__ PWh, const bf16* __restrict__ PWl,
    const float* __restrict__ pb, const float* __restrict__ emb_w,
    const int* __restrict__ label,
    bf16* __restrict__ Ph, bf16* __restrict__ Pl,
    bf16* __restrict__ Xeh, bf16* __restrict__ Xel,               // e_{tp+1} target
    int nbBlk, int tp)
{
    __shared__ float pr[4][32][17];
    int tid = threadIdx.x, wave = tid >> 6, lane = tid & 63;
    int nb = nbBlk * 16;
    int ncol = nb + (lane & 15);
    int kc = wave * 512;
    const short* ah;
    const short* al;
    size_t astr, aoff;
    if (wave < 2) { ah = (const short*)Xph; al = (const short*)Xpl; astr = KX;   aoff = kc; }
    else          { ah = (const short*)Hph; al = (const short*)Hpl; astr = 1024; aoff = kc - 1024; }
    const short* wrh = (const short*)PWh + (size_t)ncol * KP + kc + (lane >> 4) * 8;
    const short* wrl = (const short*)PWl + (size_t)ncol * KP + kc + (lane >> 4) * 8;
    size_t arow0 = (size_t)(lane & 15) * astr + aoff + (lane >> 4) * 8;
    size_t arow1 = (size_t)((lane & 15) + 16) * astr + aoff + (lane >> 4) * 8;
    f32x4 acc0 = {0, 0, 0, 0}, acc1 = {0, 0, 0, 0};
#pragma unroll 4
    for (int kk = 0; kk < 16; ++kk) {
        int ko = kk * 32;
        short8 a0h = *(const short8*)(ah + arow0 + ko);
        short8 a1h = *(const short8*)(ah + arow1 + ko);
        short8 a0l = *(const short8*)(al + arow0 + ko);
        short8 a1l = *(const short8*)(al + arow1 + ko);
        short8 bh = *(const short8*)(wrh + ko);
        short8 bl = *(const short8*)(wrl + ko);
        acc0 = MFMA(a0h, bh, acc0); acc1 = MFMA(a1h, bh, acc1);
        acc0 = MFMA(a0h, bl, acc0); acc1 = MFMA(a1h, bl, acc1);
        acc0 = MFMA(a0l, bh, acc0); acc1 = MFMA(a1l, bh, acc1);
    }
#pragma unroll
    for (int r = 0; r < 4; ++r) {
        pr[wave][(lane >> 4) * 4 + r][lane & 15]      = acc0[r];
        pr[wave][16 + (lane >> 4) * 4 + r][lane & 15] = acc1[r];
    }
    __syncthreads();
    for (int p = tid; p < 512; p += 256) {
        int bb = p >> 4, col = p & 15;
        float v = pr[0][bb][col] + pr[1][bb][col] + pr[2][bb][col] + pr[3][bb][col]
                  + pb[nb + col];
        size_t mi = (size_t)(bb * 64 + tp) * 512 + nb + col;
        Ph[mi] = bhi(v);
        Pl[mi] = blo(v);
    }
    // gather e_{tp+1} for batch b = nbBlk
    int b = nbBlk;
    int wd = label[b * 64 + tp];
    wd = wd < 0 ? 0 : (wd > V_ - 1 ? V_ - 1 : wd);
    const float* ew = emb_w + (size_t)wd * 512;
    for (int d = tid; d < 512; d += 256) {
        float v = ew[d];
        Xeh[(size_t)b * KX + 2048 + d] = bhi(v);
        Xel[(size_t)b * KX + 2048 + d] = blo(v);
    }
    __syncthreads();
}

// gates for 16-col group jbBlk (0..255): split-bf16 GEMM + fused LSTM pointwise.
// Writes cb, hb, Hn (split) only.
__device__ __forceinline__ void gates_fn(
    const bf16* __restrict__ Xh_, const bf16* __restrict__ Xl_,
    const bf16* __restrict__ Wh_, const bf16* __restrict__ Wl_,
    const float* __restrict__ bias,
    float* __restrict__ c, float* __restrict__ h,
    bf16* __restrict__ Hnh, bf16* __restrict__ Hnl, int jbBlk)
{
    __shared__ float pr2[4][32][17];
    int jb = jbBlk * 16;
    int tid = threadIdx.x, wave = tid >> 6, lane = tid & 63;
    int jcol = jb + (lane & 15);
    int kc = wave * 640 + (lane >> 4) * 8;
    const short* xhp = (const short*)Xh_ + kc;
    const short* xlp = (const short*)Xl_ + kc;
    const short* wrh = (const short*)Wh_ + (size_t)jcol * KX + kc;
    const short* wrl = (const short*)Wl_ + (size_t)jcol * KX + kc;
    size_t arow0 = (size_t)(lane & 15) * KX;
    size_t arow1 = (size_t)((lane & 15) + 16) * KX;
    f32x4 acc0 = {0, 0, 0, 0}, acc1 = {0, 0, 0, 0};
#pragma unroll 4
    for (int kk = 0; kk < 20; ++kk) {
        int ko = kk * 32;
        short8 a0h = *(const short8*)(xhp + arow0 + ko);
        short8 a1h = *(const short8*)(xhp + arow1 + ko);
        short8 a0l = *(const short8*)(xlp + arow0 + ko);
        short8 a1l = *(const short8*)(xlp + arow1 + ko);
        short8 bh = *(const short8*)(wrh + ko);
        short8 bl = *(const short8*)(wrl + ko);
        acc0 = MFMA(a0h, bh, acc0); acc1 = MFMA(a1h, bh, acc1);
        acc0 = MFMA(a0h, bl, acc0); acc1 = MFMA(a1h, bl, acc1);
        acc0 = MFMA(a0l, bh, acc0); acc1 = MFMA(a1l, bh, acc1);
    }
#pragma unroll
    for (int r = 0; r < 4; ++r) {
        pr2[wave][(lane >> 4) * 4 + r][lane & 15]      = acc0[r];
        pr2[wave][16 + (lane >> 4) * 4 + r][lane & 15] = acc1[r];
    }
    __syncthreads();
    if (tid < 128) {
        int bb = tid & 31, dd = tid >> 5;
        int cb2 = dd * 4;
        float gi = pr2[0][bb][cb2+0] + pr2[1][bb][cb2+0] + pr2[2][bb][cb2+0] + pr2[3][bb][cb2+0] + bias[jb+cb2+0];
        float gf = pr2[0][bb][cb2+1] + pr2[1][bb][cb2+1] + pr2[2][bb][cb2+1] + pr2[3][bb][cb2+1] + bias[jb+cb2+1];
        float gg = pr2[0][bb][cb2+2] + pr2[1][bb][cb2+2] + pr2[2][bb][cb2+2] + pr2[3][bb][cb2+2] + bias[jb+cb2+2];
        float go = pr2[0][bb][cb2+3] + pr2[1][bb][cb2+3] + pr2[2][bb][cb2+3] + pr2[3][bb][cb2+3] + bias[jb+cb2+3];
        int d = (jb >> 2) + dd;
        float cv = c[bb * 1024 + d];
        float cn = sigmoidf_(gf) * cv + sigmoidf_(gi) * tanhf(gg);
        float hn = sigmoidf_(go) * tanhf(cn);
        c[bb * 1024 + d] = cn;
        h[bb * 1024 + d] = hn;
        Hnh[bb * 1024 + d] = bhi(hn);
        Hnl[bb * 1024 + d] = blo(hn);
    }
    __syncthreads();
}

// ---------------- persistent cooperative T-loop ----------------

__global__ __launch_bounds__(256, 2) void k_loop(
    const float* enc, const float* mask, const int* label, const float* emb_w,
    const bf16* PWh, const bf16* PWl, const float* pb,
    const bf16* Wgh, const bf16* Wgl, const float* bias,
    float* hb, float* cb,
    bf16* X0h, bf16* X0l, bf16* X1h, bf16* X1l,
    bf16* H0h, bf16* H0l, bf16* H1h, bf16* H1l,
    bf16* Ph, bf16* Pl, float* pml, float* pctx)
{
    cg::grid_group grid = cg::this_grid();
    int bid = blockIdx.x;

    for (int t = 0; t <= T_; ++t) {
        int p = t & 1;
        bf16* Xch = p ? X1h : X0h;         // X of current parity
        bf16* Xcl = p ? X1l : X0l;
        const bf16* Xph = p ? X0h : X1h;   // X of previous parity (ctx_{t-1})
        const bf16* Xpl = p ? X0l : X1l;
        const bf16* Hth = p ? H1h : H0h;   // h_t (split)
        const bf16* Htl = p ? H1l : H0l;
        bf16* Hnh = p ? H0h : H1h;         // h_{t+1} target
        bf16* Hnl = p ? H0l : H1l;

        if (t < T_) {
            // Phase A: attention partials (1024 units over 512 blocks)
            att_unit(enc, mask, hb, pml, pctx, (bid * 2) >> 5, (bid * 2) & 31);
            att_unit(enc, mask, hb, pml, pctx, (bid * 2 + 1) >> 5, (bid * 2 + 1) & 31);
            grid.sync();
        }
        // Phase B: comb(t) on blocks 0-31; proj(t-1) on blocks 32-63
        if (bid < 32) {
            if (t < T_) comb_fn(pml, pctx, Hth, Htl, Xch, Xcl, bid);
        } else if (bid < 64 && t >= 1) {
            proj_fn(Xph, Xpl, Hth, Htl, PWh, PWl, pb, emb_w, label,
                    Ph, Pl, Xch, Xcl, bid - 32, t - 1);
        }
        if (t < T_) {
            grid.sync();
            // Phase C: gates(t) on blocks 0-255
            if (bid < 256)
                gates_fn(Xch, Xcl, Wgh, Wgl, bias, cb, hb, Hnh, Hnl, bid);
            grid.sync();
        }
    }
}

// ---------------- fallback wrappers (if cooperative launch unavailable) ----------------

__global__ __launch_bounds__(256) void k_attw(
    const float* enc, const float* mask, const float* hb,
    float* pml, float* pctx)
{
    int unit = blockIdx.x;
    att_unit(enc, mask, hb, pml, pctx, unit >> 5, unit & 31);
}

__global__ __launch_bounds__(256) void k_cpw(
    const int* label, const float* emb_w,
    const bf16* PWh, const bf16* PWl, const float* pb,
    bf16* X0h, bf16* X0l, bf16* X1h, bf16* X1l,
    bf16* H0h, bf16* H0l, bf16* H1h, bf16* H1l,
    bf16* Ph, bf16* Pl, float* pml, float* pctx, int t)
{
    int p = t & 1;
    bf16* Xch = p ? X1h : X0h;
    bf16* Xcl = p ? X1l : X0l;
    const bf16* Xph = p ? X0h : X1h;
    const bf16* Xpl = p ? X0l : X1l;
    const bf16* Hth = p ? H1h : H0h;
    const bf16* Htl = p ? H1l : H0l;
    int bid = blockIdx.x;
    if (bid < 32) {
        if (t < T_) comb_fn(pml, pctx, Hth, Htl, Xch, Xcl, bid);
    } else if (t >= 1) {
        proj_fn(Xph, Xpl, Hth, Htl, PWh, PWl, pb, emb_w, label,
                Ph, Pl, Xch, Xcl, bid - 32, t - 1);
    }
}

__global__ __launch_bounds__(256) void k_gatesw(
    const bf16* Wgh, const bf16* Wgl, const float* bias,
    float* cb, float* hb,
    bf16* X0h, bf16* X0l, bf16* X1h, bf16* X1l,
    bf16* H0h, bf16* H0l, bf16* H1h, bf16* H1l, int t)
{
    int p = t & 1;
    const bf16* Xch = p ? X1h : X0h;
    const bf16* Xcl = p ? X1l : X0l;
    bf16* Hnh = p ? H0h : H1h;
    bf16* Hnl = p ? H0l : H1l;
    gates_fn(Xch, Xcl, Wgh, Wgl, bias, cb, hb, Hnh, Hnl, blockIdx.x);
}

// ---------------- final vocab GEMM (R4 config, measured 339us) ----------------

__global__ __launch_bounds__(256) void k_out(const bf16* __restrict__ Ph,
                                             const bf16* __restrict__ Pl,
                                             const bf16* __restrict__ Eb,
                                             float* __restrict__ out) {
    int bid = blockIdx.x;
    int vb = (bid >> 5) * 64;
    int mb = (bid & 31) * 64;
    __shared__ __align__(16) short ph[64][264];
    __shared__ __align__(16) short pl[64][264];
    int tid = threadIdx.x, wave = tid >> 6, lane = tid & 63;
    int wr = (wave >> 1) * 32, wc = (wave & 1) * 32;
    f32x4 acc[2][2] = {{{0, 0, 0, 0}, {0, 0, 0, 0}}, {{0, 0, 0, 0}, {0, 0, 0, 0}}};
    const short* e0 = (const short*)Eb + (size_t)(vb + wc + (lane & 15)) * 512 + (lane >> 4) * 8;
    const short* e1 = e0 + 16 * 512;

    for (int q = 0; q < 2; ++q) {
        __syncthreads();
        for (int i = tid; i < 64 * 32; i += 256) {
            int r = i >> 5, cc = i & 31;
            ((short8*)&ph[r][0])[cc] = *(const short8*)((const short*)Ph + (size_t)(mb + r) * 512 + q * 256 + cc * 8);
            ((short8*)&pl[r][0])[cc] = *(const short8*)((const short*)Pl + (size_t)(mb + r) * 512 + q * 256 + cc * 8);
        }
        __syncthreads();
#pragma unroll
        for (int kk = 0; kk < 8; ++kk) {
            int kcol = kk * 32 + (lane >> 4) * 8;
            short8 a0h = *(const short8*)(&ph[wr + (lane & 15)][kcol]);
            short8 a1h = *(const short8*)(&ph[wr + 16 + (lane & 15)][kcol]);
            short8 a0l = *(const short8*)(&pl[wr + (lane & 15)][kcol]);
            short8 a1l = *(const short8*)(&pl[wr + 16 + (lane & 15)][kcol]);
            short8 b0 = *(const short8*)(e0 + q * 256 + kk * 32);
            short8 b1 = *(const short8*)(e1 + q * 256 + kk * 32);
            acc[0][0] = MFMA(a0h, b0, acc[0][0]);
            acc[0][1] = MFMA(a0h, b1, acc[0][1]);
            acc[1][0] = MFMA(a1h, b0, acc[1][0]);
            acc[1][1] = MFMA(a1h, b1, acc[1][1]);
            acc[0][0] = MFMA(a0l, b0, acc[0][0]);
            acc[0][1] = MFMA(a0l, b1, acc[0][1]);
            acc[1][0] = MFMA(a1l, b0, acc[1][0]);
            acc[1][1] = MFMA(a1l, b1, acc[1][1]);
        }
    }
#pragma unroll
    for (int f0 = 0; f0 < 2; ++f0)
#pragma unroll
        for (int f1 = 0; f1 < 2; ++f1)
#pragma unroll
            for (int r = 0; r < 4; ++r) {
                int mm = mb + wr + 16 * f0 + (lane >> 4) * 4 + r;
                int vv = vb + wc + 16 * f1 + (lane & 15);
                __builtin_nontemporal_store(acc[f0][f1][r], &out[(size_t)mm * V_ + vv]);
            }
}

// ---------------- launcher ----------------

extern "C" void kernel_launch(void* const* d_in, const int* in_sizes, int n_in,
                              void* d_out, int out_size, void* d_ws, size_t ws_size,
                              hipStream_t stream) {
    (void)in_sizes; (void)n_in; (void)out_size; (void)ws_size;
    const float* enc    = (const float*)d_in[0];
    const float* mask   = (const float*)d_in[1];
    const int*   label  = (const int*)d_in[2];
    const float* emb_w  = (const float*)d_in[3];
    const float* W_ih   = (const float*)d_in[4];
    const float* b_ih   = (const float*)d_in[5];
    const float* W_hh   = (const float*)d_in[6];
    const float* b_hh   = (const float*)d_in[7];
    const float* proj_W = (const float*)d_in[8];
    const float* proj_b = (const float*)d_in[9];
    const float* emb0   = (const float*)d_in[10];
    const float* h0     = (const float*)d_in[11];
    const float* c0     = (const float*)d_in[12];
    float* out = (float*)d_out;

    char* w = (char*)d_ws;
    size_t o = 0;
    bf16* Wgh  = (bf16*)(w + o); o += (size_t)4096 * KX * 2;     // 21.0 MB
    bf16* Wgl  = (bf16*)(w + o); o += (size_t)4096 * KX * 2;     // 21.0 MB
    bf16* PWh  = (bf16*)(w + o); o += (size_t)512 * KP * 2;      // 2.1 MB
    bf16* PWl  = (bf16*)(w + o); o += (size_t)512 * KP * 2;      // 2.1 MB
    bf16* Eb   = (bf16*)(w + o); o += (size_t)V_ * 512 * 2;      // 32.8 MB
    float* bias= (float*)(w + o); o += 4096 * 4;
    bf16* X0h  = (bf16*)(w + o); o += (size_t)32 * KX * 2;
    bf16* X0l  = (bf16*)(w + o); o += (size_t)32 * KX * 2;
    bf16* X1h  = (bf16*)(w + o); o += (size_t)32 * KX * 2;
    bf16* X1l  = (bf16*)(w + o); o += (size_t)32 * KX * 2;
    bf16* H0h  = (bf16*)(w + o); o += (size_t)32 * 1024 * 2;
    bf16* H0l  = (bf16*)(w + o); o += (size_t)32 * 1024 * 2;
    bf16* H1h  = (bf16*)(w + o); o += (size_t)32 * 1024 * 2;
    bf16* H1l  = (bf16*)(w + o); o += (size_t)32 * 1024 * 2;
    bf16* Ph   = (bf16*)(w + o); o += (size_t)2048 * 512 * 2;    // 2.1 MB
    bf16* Pl   = (bf16*)(w + o); o += (size_t)2048 * 512 * 2;    // 2.1 MB
    float* hb  = (float*)(w + o); o += (size_t)32 * 1024 * 4;
    float* cb  = (float*)(w + o); o += (size_t)32 * 1024 * 4;
    float* pml = (float*)(w + o); o += (size_t)32 * NCH * 2 * 4;
    float* pctx= (float*)(w + o); o += (size_t)32 * NCH * 1024 * 4;  // 4.2 MB
    // total ~86 MB

    k_build_wg<<<4096, 256, 0, stream>>>(W_ih, W_hh, b_ih, b_hh, Wgh, Wgl, bias);
    k_cvt_split<<<1024, 256, 0, stream>>>(proj_W, PWh, PWl, (long)512 * KP);
    k_cvt<<<8192, 256, 0, stream>>>(emb_w, Eb, (long)V_ * 512);
    k_init<<<32, 256, 0, stream>>>(h0, c0, emb0, hb, cb, H0h, H0l, X0h, X0l);

    void* kargs[] = {
        (void*)&enc, (void*)&mask, (void*)&label, (void*)&emb_w,
        (void*)&PWh, (void*)&PWl, (void*)&proj_b,
        (void*)&Wgh, (void*)&Wgl, (void*)&bias,
        (void*)&hb, (void*)&cb,
        (void*)&X0h, (void*)&X0l, (void*)&X1h, (void*)&X1l,
        (void*)&H0h, (void*)&H0l, (void*)&H1h, (void*)&H1l,
        (void*)&Ph, (void*)&Pl, (void*)&pml, (void*)&pctx };
    hipError_t cerr = hipLaunchCooperativeKernel((void*)k_loop, dim3(512), dim3(256),
                                                 kargs, 0u, stream);
    if (cerr != hipSuccess) {
        // fallback: same phases as discrete dispatches (R9-equivalent)
        for (int t = 0; t <= T_; ++t) {
            if (t < T_)
                k_attw<<<1024, 256, 0, stream>>>(enc, mask, hb, pml, pctx);
            k_cpw<<<64, 256, 0, stream>>>(label, emb_w, PWh, PWl, proj_b,
                                          X0h, X0l, X1h, X1l,
                                          H0h, H0l, H1h, H1l,
                                          Ph, Pl, pml, pctx, t);
            if (t < T_)
                k_gatesw<<<256, 256, 0, stream>>>(Wgh, Wgl, bias, cb, hb,
                                                  X0h, X0l, X1h, X1l,
                                                  H0h, H0l, H1h, H1l, t);
        }
    }
    k_out<<<16000, 256, 0, stream>>>(Ph, Pl, Eb, out);
}

// Round 13
// 3334.149 us; speedup vs baseline: 4.0864x; 4.0864x over previous
//
#include <hip/hip_runtime.h>
#include <hip/hip_bf16.h>

// Decoder: attention + LSTMCell + proj + vocab scoring.
// B=32, S=512, T=64, DENC=DHID=1024, DEMB=512, V=32000.
// Precision: recurrent state f32; GEMMs split-bf16 (hi/lo, 3 MFMA chains).
// Structure (race-free, R9): k_att [proj(t-1)+att partials] -> k_comb -> k_gates.
// R13: R9 loop verbatim (cooperative experiment reverted — grid.sync costs
//      ~70us on 8-XCD MI355X). k_out rewritten m97-style: 128x128 tile, BK=32,
//      padded LDS (A_hi/A_lo/B), B-frags shared across hi/lo chains, 27KB LDS
//      -> 3-4 blocks/CU, m-inner grid for Eb L2 reuse.

#define B_   32
#define S_   512
#define T_   64
#define DENC 1024
#define DHID 1024
#define DEMB 512
#define V_   32000
#define KX   2560   // X row: [ctx 1024 | h 1024 | e 512]
#define KP   2048   // proj K: [ctx | h]
#define NCH  32     // attention s-chunks per batch (16 rows each)

using short8 = __attribute__((ext_vector_type(8))) short;
using f32x4  = __attribute__((ext_vector_type(4))) float;
typedef __hip_bfloat16 bf16;

__device__ __forceinline__ float sigmoidf_(float x) { return 1.0f / (1.0f + expf(-x)); }
__device__ __forceinline__ bf16 bhi(float x) { return __float2bfloat16(x); }
__device__ __forceinline__ bf16 blo(float x) {
    return __float2bfloat16(x - __bfloat162float(__float2bfloat16(x)));
}

#define MFMA(a, b, c) __builtin_amdgcn_mfma_f32_16x16x32_bf16((a), (b), (c), 0, 0, 0)
#define DOT4(a, b) fmaf((a).x, (b).x, fmaf((a).y, (b).y, fmaf((a).z, (b).z, (a).w * (b).w)))

// ---------------- setup kernels ----------------

__global__ void k_build_wg(const float* __restrict__ W_ih, const float* __restrict__ W_hh,
                           const float* __restrict__ b_ih, const float* __restrict__ b_hh,
                           bf16* __restrict__ Wh, bf16* __restrict__ Wl, float* __restrict__ bias) {
    int jp = blockIdx.x;            // 0..4095, j' = d*4 + gate
    int g = jp & 3, d = jp >> 2;
    int j = g * 1024 + d;           // source row (torch gate order i,f,g,o)
    const float* wi = W_ih + (size_t)j * 1536;
    const float* wh = W_hh + (size_t)j * 1024;
    bf16* dh = Wh + (size_t)jp * KX;
    bf16* dl = Wl + (size_t)jp * KX;
    for (int i = threadIdx.x; i < 1024; i += 256) { float v = wi[i];      dh[i] = bhi(v);        dl[i] = blo(v); }
    for (int i = threadIdx.x; i < 1024; i += 256) { float v = wh[i];      dh[1024+i] = bhi(v);   dl[1024+i] = blo(v); }
    for (int i = threadIdx.x; i < 512;  i += 256) { float v = wi[1024+i]; dh[2048+i] = bhi(v);   dl[2048+i] = blo(v); }
    if (threadIdx.x == 0) bias[jp] = b_ih[j] + b_hh[j];
}

__global__ void k_cvt(const float* __restrict__ src, bf16* __restrict__ dst, long n) {
    long i = (long)blockIdx.x * blockDim.x + threadIdx.x;
    long stride = (long)gridDim.x * blockDim.x;
    for (; i < n; i += stride) dst[i] = __float2bfloat16(src[i]);
}

__global__ void k_cvt_split(const float* __restrict__ src, bf16* __restrict__ dh,
                            bf16* __restrict__ dl, long n) {
    long i = (long)blockIdx.x * blockDim.x + threadIdx.x;
    long stride = (long)gridDim.x * blockDim.x;
    for (; i < n; i += stride) { float v = src[i]; dh[i] = bhi(v); dl[i] = blo(v); }
}

__global__ void k_init(const float* __restrict__ h0, const float* __restrict__ c0,
                       const float* __restrict__ emb0,
                       float* __restrict__ h, float* __restrict__ c,
                       bf16* __restrict__ Hh, bf16* __restrict__ Hl,
                       bf16* __restrict__ Xh_, bf16* __restrict__ Xl_) {
    int b = blockIdx.x;   // 32 blocks
    for (int d = threadIdx.x; d < 1024; d += 256) {
        float v = h0[d];
        h[b * 1024 + d] = v;
        c[b * 1024 + d] = c0[d];
        Hh[b * 1024 + d] = bhi(v);
        Hl[b * 1024 + d] = blo(v);
    }
    for (int d = threadIdx.x; d < 512; d += 256) {
        float v = emb0[d];
        Xh_[(size_t)b * KX + 2048 + d] = bhi(v);
        Xl_[(size_t)b * KX + 2048 + d] = blo(v);
    }
}

// ---------------- per-step kernel 1: proj(t-1) + attention partials(t) ----------------

__global__ __launch_bounds__(256) void k_att(
    const float* __restrict__ enc, const float* __restrict__ mask,
    const float* __restrict__ h,
    bf16* __restrict__ Xh_, bf16* __restrict__ Xl_,
    const bf16* __restrict__ Hh, const bf16* __restrict__ Hl,
    const bf16* __restrict__ PWh, const bf16* __restrict__ PWl,
    const float* __restrict__ pb, const float* __restrict__ emb_w,
    const int* __restrict__ label,
    bf16* __restrict__ Ph, bf16* __restrict__ Pl,
    float* __restrict__ pml, float* __restrict__ pctx, int t)
{
    __shared__ float pr[4][32][17];
    __shared__ float lctx[4][1024];
    __shared__ float lm[4], ll[4];

    int bid = blockIdx.x;
    int tid = threadIdx.x, wave = tid >> 6, lane = tid & 63;

    if (bid < 32) {
        // ---------- proj for step t-1: p = [ctx_{t-1} | h_t] @ PW^T + pb ----------
        if (t == 0) return;
        int tp = t - 1;
        int nb = bid * 16;
        int ncol = nb + (lane & 15);
        int kc = wave * 512;
        const short* ah;
        const short* al;
        size_t astr, aoff;
        if (wave < 2) { ah = (const short*)Xh_; al = (const short*)Xl_; astr = KX;   aoff = kc; }
        else          { ah = (const short*)Hh;  al = (const short*)Hl;  astr = 1024; aoff = kc - 1024; }
        const short* wrh = (const short*)PWh + (size_t)ncol * KP + kc + (lane >> 4) * 8;
        const short* wrl = (const short*)PWl + (size_t)ncol * KP + kc + (lane >> 4) * 8;
        size_t arow0 = (size_t)(lane & 15) * astr + aoff + (lane >> 4) * 8;
        size_t arow1 = (size_t)((lane & 15) + 16) * astr + aoff + (lane >> 4) * 8;
        f32x4 acc0 = {0, 0, 0, 0}, acc1 = {0, 0, 0, 0};
#pragma unroll 4
        for (int kk = 0; kk < 16; ++kk) {
            int ko = kk * 32;
            short8 a0h = *(const short8*)(ah + arow0 + ko);
            short8 a1h = *(const short8*)(ah + arow1 + ko);
            short8 a0l = *(const short8*)(al + arow0 + ko);
            short8 a1l = *(const short8*)(al + arow1 + ko);
            short8 bh = *(const short8*)(wrh + ko);
            short8 bl = *(const short8*)(wrl + ko);
            acc0 = MFMA(a0h, bh, acc0); acc1 = MFMA(a1h, bh, acc1);
            acc0 = MFMA(a0h, bl, acc0); acc1 = MFMA(a1h, bl, acc1);
            acc0 = MFMA(a0l, bh, acc0); acc1 = MFMA(a1l, bh, acc1);
        }
#pragma unroll
        for (int r = 0; r < 4; ++r) {
            pr[wave][(lane >> 4) * 4 + r][lane & 15]      = acc0[r];
            pr[wave][16 + (lane >> 4) * 4 + r][lane & 15] = acc1[r];
        }
        __syncthreads();
        for (int p = tid; p < 512; p += 256) {
            int bb = p >> 4, col = p & 15;
            float v = pr[0][bb][col] + pr[1][bb][col] + pr[2][bb][col] + pr[3][bb][col]
                      + pb[nb + col];
            size_t mi = (size_t)(bb * 64 + tp) * 512 + nb + col;
            Ph[mi] = bhi(v);
            Pl[mi] = blo(v);
        }
        int b = bid;
        int wd = label[b * 64 + tp];
        wd = wd < 0 ? 0 : (wd > V_ - 1 ? V_ - 1 : wd);
        const float* ew = emb_w + (size_t)wd * 512;
        for (int d = tid; d < 512; d += 256) {
            float v = ew[d];
            Xh_[(size_t)b * KX + 2048 + d] = bhi(v);
            Xl_[(size_t)b * KX + 2048 + d] = blo(v);
        }
        return;
    }

    // ---------- attention partials for step t ----------
    if (t >= T_) return;
    int ab = bid - 32;
    int b = ab >> 5, ch = ab & (NCH - 1);

    float4 hreg[4];
    const float4* h4p = (const float4*)(h + b * 1024);
#pragma unroll
    for (int j = 0; j < 4; ++j) hreg[j] = h4p[j * 64 + lane];

    const float* encb = enc + (size_t)b * S_ * DENC;
    int srow0 = ch * 16 + wave * 4;
    const float4* r0 = (const float4*)(encb + (size_t)(srow0 + 0) * DENC);
    const float4* r1 = (const float4*)(encb + (size_t)(srow0 + 1) * DENC);
    const float4* r2 = (const float4*)(encb + (size_t)(srow0 + 2) * DENC);
    const float4* r3 = (const float4*)(encb + (size_t)(srow0 + 3) * DENC);
    float4 e00 = r0[lane], e01 = r0[64+lane], e02 = r0[128+lane], e03 = r0[192+lane];
    float4 e10 = r1[lane], e11 = r1[64+lane], e12 = r1[128+lane], e13 = r1[192+lane];
    float4 e20 = r2[lane], e21 = r2[64+lane], e22 = r2[128+lane], e23 = r2[192+lane];
    float4 e30 = r3[lane], e31 = r3[64+lane], e32 = r3[128+lane], e33 = r3[192+lane];

    float d0 = DOT4(e00,hreg[0]) + DOT4(e01,hreg[1]) + DOT4(e02,hreg[2]) + DOT4(e03,hreg[3]);
    float d1 = DOT4(e10,hreg[0]) + DOT4(e11,hreg[1]) + DOT4(e12,hreg[2]) + DOT4(e13,hreg[3]);
    float d2 = DOT4(e20,hreg[0]) + DOT4(e21,hreg[1]) + DOT4(e22,hreg[2]) + DOT4(e23,hreg[3]);
    float d3 = DOT4(e30,hreg[0]) + DOT4(e31,hreg[1]) + DOT4(e32,hreg[2]) + DOT4(e33,hreg[3]);
#pragma unroll
    for (int off = 32; off; off >>= 1) {
        d0 += __shfl_xor(d0, off, 64);
        d1 += __shfl_xor(d1, off, 64);
        d2 += __shfl_xor(d2, off, 64);
        d3 += __shfl_xor(d3, off, 64);
    }
    float sc0 = d0 - (1.0f - mask[b * S_ + srow0 + 0]) * 1e20f;
    float sc1 = d1 - (1.0f - mask[b * S_ + srow0 + 1]) * 1e20f;
    float sc2 = d2 - (1.0f - mask[b * S_ + srow0 + 2]) * 1e20f;
    float sc3 = d3 - (1.0f - mask[b * S_ + srow0 + 3]) * 1e20f;
    float mw = fmaxf(fmaxf(sc0, sc1), fmaxf(sc2, sc3));
    float w0 = expf(sc0 - mw), w1 = expf(sc1 - mw);
    float w2 = expf(sc2 - mw), w3 = expf(sc3 - mw);
    float lw = w0 + w1 + w2 + w3;
    float4 c0, c1, c2, c3;
    c0.x = w0*e00.x + w1*e10.x + w2*e20.x + w3*e30.x;
    c0.y = w0*e00.y + w1*e10.y + w2*e20.y + w3*e30.y;
    c0.z = w0*e00.z + w1*e10.z + w2*e20.z + w3*e30.z;
    c0.w = w0*e00.w + w1*e10.w + w2*e20.w + w3*e30.w;
    c1.x = w0*e01.x + w1*e11.x + w2*e21.x + w3*e31.x;
    c1.y = w0*e01.y + w1*e11.y + w2*e21.y + w3*e31.y;
    c1.z = w0*e01.z + w1*e11.z + w2*e21.z + w3*e31.z;
    c1.w = w0*e01.w + w1*e11.w + w2*e21.w + w3*e31.w;
    c2.x = w0*e02.x + w1*e12.x + w2*e22.x + w3*e32.x;
    c2.y = w0*e02.y + w1*e12.y + w2*e22.y + w3*e32.y;
    c2.z = w0*e02.z + w1*e12.z + w2*e22.z + w3*e32.z;
    c2.w = w0*e02.w + w1*e12.w + w2*e22.w + w3*e32.w;
    c3.x = w0*e03.x + w1*e13.x + w2*e23.x + w3*e33.x;
    c3.y = w0*e03.y + w1*e13.y + w2*e23.y + w3*e33.y;
    c3.z = w0*e03.z + w1*e13.z + w2*e23.z + w3*e33.z;
    c3.w = w0*e03.w + w1*e13.w + w2*e23.w + w3*e33.w;

    ((float4*)lctx[wave])[0 * 64 + lane] = c0;
    ((float4*)lctx[wave])[1 * 64 + lane] = c1;
    ((float4*)lctx[wave])[2 * 64 + lane] = c2;
    ((float4*)lctx[wave])[3 * 64 + lane] = c3;
    if (lane == 0) { lm[wave] = mw; ll[wave] = lw; }
    __syncthreads();

    float mb_ = fmaxf(fmaxf(lm[0], lm[1]), fmaxf(lm[2], lm[3]));
    float q0 = expf(lm[0] - mb_), q1 = expf(lm[1] - mb_);
    float q2 = expf(lm[2] - mb_), q3 = expf(lm[3] - mb_);
    float lb = ll[0] * q0 + ll[1] * q1 + ll[2] * q2 + ll[3] * q3;
    float4 a0 = ((float4*)lctx[0])[tid], a1 = ((float4*)lctx[1])[tid];
    float4 a2 = ((float4*)lctx[2])[tid], a3 = ((float4*)lctx[3])[tid];
    float4 v;
    v.x = a0.x * q0 + a1.x * q1 + a2.x * q2 + a3.x * q3;
    v.y = a0.y * q0 + a1.y * q1 + a2.y * q2 + a3.y * q3;
    v.z = a0.z * q0 + a1.z * q1 + a2.z * q2 + a3.z * q3;
    v.w = a0.w * q0 + a1.w * q1 + a2.w * q2 + a3.w * q3;
    int pi = b * NCH + ch;
    ((float4*)(pctx + (size_t)pi * 1024))[tid] = v;
    if (tid == 0) { pml[pi * 2] = mb_; pml[pi * 2 + 1] = lb; }
}

// ---------------- per-step kernel 2: combine partials -> X.ctx, copy H -> X.h ----------------

__global__ __launch_bounds__(256) void k_comb(const float* __restrict__ pml,
                                              const float* __restrict__ pctx,
                                              const bf16* __restrict__ Hh,
                                              const bf16* __restrict__ Hl,
                                              bf16* __restrict__ Xh_, bf16* __restrict__ Xl_) {
    __shared__ float sml[NCH * 2];
    __shared__ float wch[NCH];
    int b = blockIdx.x, tid = threadIdx.x;
    if (tid < NCH * 2) sml[tid] = pml[b * NCH * 2 + tid];
    __syncthreads();
    float mf = -3.0e38f;
#pragma unroll
    for (int c = 0; c < NCH; ++c) mf = fmaxf(mf, sml[2 * c]);
    float lt = 0.f;
#pragma unroll
    for (int c = 0; c < NCH; ++c) lt += sml[2 * c + 1] * expf(sml[2 * c] - mf);
    if (tid < NCH) wch[tid] = expf(sml[2 * tid] - mf);
    __syncthreads();
    float inv = 1.0f / lt;
    const float4* base = (const float4*)(pctx + (size_t)b * NCH * 1024) + tid;
    float4 sacc = {0, 0, 0, 0};
#pragma unroll 8
    for (int c = 0; c < NCH; ++c) {
        float wc = wch[c];
        float4 p = base[c * 256];
        sacc.x = fmaf(wc, p.x, sacc.x); sacc.y = fmaf(wc, p.y, sacc.y);
        sacc.z = fmaf(wc, p.z, sacc.z); sacc.w = fmaf(wc, p.w, sacc.w);
    }
    sacc.x *= inv; sacc.y *= inv; sacc.z *= inv; sacc.w *= inv;
    size_t xi = (size_t)b * KX + tid * 4;
    Xh_[xi + 0] = bhi(sacc.x); Xl_[xi + 0] = blo(sacc.x);
    Xh_[xi + 1] = bhi(sacc.y); Xl_[xi + 1] = blo(sacc.y);
    Xh_[xi + 2] = bhi(sacc.z); Xl_[xi + 2] = blo(sacc.z);
    Xh_[xi + 3] = bhi(sacc.w); Xl_[xi + 3] = blo(sacc.w);
    ((unsigned long long*)(Xh_ + (size_t)b * KX + 1024))[tid] =
        ((const unsigned long long*)(Hh + (size_t)b * 1024))[tid];
    ((unsigned long long*)(Xl_ + (size_t)b * KX + 1024))[tid] =
        ((const unsigned long long*)(Hl + (size_t)b * 1024))[tid];
}

// ---------------- per-step kernel 3: gates ----------------

// gates = X[32x2560] @ Wg^T[4096x2560] + bias (split-bf16, 3 chains), fused LSTM
// pointwise. grid 256: block = 16 cols; 4 waves = 4-way K-split; LDS reduce.
// Epilogue writes cb, hb (f32) and H (split bf16) ONLY — never X (race-free).
__global__ __launch_bounds__(256) void k_gates(
    const bf16* __restrict__ Xh_, const bf16* __restrict__ Xl_,
    const bf16* __restrict__ Wh_, const bf16* __restrict__ Wl_,
    const float* __restrict__ bias,
    float* __restrict__ c, float* __restrict__ h,
    bf16* __restrict__ Hh, bf16* __restrict__ Hl)
{
    __shared__ float pr[4][32][17];
    int jb = blockIdx.x * 16;
    int tid = threadIdx.x, wave = tid >> 6, lane = tid & 63;
    int jcol = jb + (lane & 15);
    int kc = wave * 640 + (lane >> 4) * 8;
    const short* xhp = (const short*)Xh_ + kc;
    const short* xlp = (const short*)Xl_ + kc;
    const short* wrh = (const short*)Wh_ + (size_t)jcol * KX + kc;
    const short* wrl = (const short*)Wl_ + (size_t)jcol * KX + kc;
    size_t arow0 = (size_t)(lane & 15) * KX;
    size_t arow1 = (size_t)((lane & 15) + 16) * KX;
    f32x4 acc0 = {0, 0, 0, 0}, acc1 = {0, 0, 0, 0};
#pragma unroll 4
    for (int kk = 0; kk < 20; ++kk) {
        int ko = kk * 32;
        short8 a0h = *(const short8*)(xhp + arow0 + ko);
        short8 a1h = *(const short8*)(xhp + arow1 + ko);
        short8 a0l = *(const short8*)(xlp + arow0 + ko);
        short8 a1l = *(const short8*)(xlp + arow1 + ko);
        short8 bh = *(const short8*)(wrh + ko);
        short8 bl = *(const short8*)(wrl + ko);
        acc0 = MFMA(a0h, bh, acc0); acc1 = MFMA(a1h, bh, acc1);
        acc0 = MFMA(a0h, bl, acc0); acc1 = MFMA(a1h, bl, acc1);
        acc0 = MFMA(a0l, bh, acc0); acc1 = MFMA(a1l, bh, acc1);
    }
#pragma unroll
    for (int r = 0; r < 4; ++r) {
        pr[wave][(lane >> 4) * 4 + r][lane & 15]      = acc0[r];
        pr[wave][16 + (lane >> 4) * 4 + r][lane & 15] = acc1[r];
    }
    __syncthreads();
    if (tid < 128) {
        int bb = tid & 31, dd = tid >> 5;
        int cb = dd * 4;
        float gi = pr[0][bb][cb+0] + pr[1][bb][cb+0] + pr[2][bb][cb+0] + pr[3][bb][cb+0] + bias[jb+cb+0];
        float gf = pr[0][bb][cb+1] + pr[1][bb][cb+1] + pr[2][bb][cb+1] + pr[3][bb][cb+1] + bias[jb+cb+1];
        float gg = pr[0][bb][cb+2] + pr[1][bb][cb+2] + pr[2][bb][cb+2] + pr[3][bb][cb+2] + bias[jb+cb+2];
        float go = pr[0][bb][cb+3] + pr[1][bb][cb+3] + pr[2][bb][cb+3] + pr[3][bb][cb+3] + bias[jb+cb+3];
        int d = (jb >> 2) + dd;
        float cv = c[bb * 1024 + d];
        float cn = sigmoidf_(gf) * cv + sigmoidf_(gi) * tanhf(gg);
        float hn = sigmoidf_(go) * tanhf(cn);
        c[bb * 1024 + d] = cn;
        h[bb * 1024 + d] = hn;
        Hh[bb * 1024 + d] = bhi(hn);
        Hl[bb * 1024 + d] = blo(hn);
    }
}

// ---------------- final vocab GEMM (m97-style 128x128 tile) ----------------

// OUT[m][v] = P[m][:] . emb_w[v][:]. P split hi/lo share one accumulator chain
// (acc += A_hi*B + A_lo*B). Tile 128x128, BK=32, K=512 -> 16 steps.
// 4 waves, wave tile 64x64 (4x4 frags of 16x16). LDS: A_hi/A_lo/B [128][36]
// padded (72B row stride -> conflict-free ds_read_b128). 27.6KB LDS.
// Grid 4000 = 250 vb x 16 mb, m-inner (consecutive blocks share Eb panel in L2).
__global__ __launch_bounds__(256) void k_out(const bf16* __restrict__ Ph,
                                             const bf16* __restrict__ Pl,
                                             const bf16* __restrict__ Eb,
                                             float* __restrict__ out) {
    int bid = blockIdx.x;
    int vb = (bid >> 4) * 128;
    int mb = (bid & 15) * 128;

    __shared__ __align__(16) short Ah[128][36];
    __shared__ __align__(16) short Al[128][36];
    __shared__ __align__(16) short Bs[128][36];

    int tid = threadIdx.x, wave = tid >> 6, lane = tid & 63;
    int wr = (wave >> 1) * 64, wc = (wave & 1) * 64;
    int fr = lane & 15, kg = lane >> 4;          // frag row lane, k-group (kg*8)

    f32x4 acc[4][4];
#pragma unroll
    for (int m = 0; m < 4; ++m)
#pragma unroll
        for (int n = 0; n < 4; ++n) acc[m][n] = (f32x4){0, 0, 0, 0};

    const short* Pp = (const short*)Ph;
    const short* Plp = (const short*)Pl;
    const short* Ep = (const short*)Eb;

    for (int ks = 0; ks < 16; ++ks) {
        int k0 = ks * 32;
        __syncthreads();
#pragma unroll
        for (int j = 0; j < 2; ++j) {
            int cch = tid + j * 256;             // 512 chunks of 8 shorts
            int r = cch >> 2, cg = (cch & 3) * 8;
            *(short8*)&Ah[r][cg] = *(const short8*)(Pp  + (size_t)(mb + r) * 512 + k0 + cg);
            *(short8*)&Al[r][cg] = *(const short8*)(Plp + (size_t)(mb + r) * 512 + k0 + cg);
            *(short8*)&Bs[r][cg] = *(const short8*)(Ep  + (size_t)(vb + r) * 512 + k0 + cg);
        }
        __syncthreads();
        short8 afh[4], afl[4], bf_[4];
#pragma unroll
        for (int m = 0; m < 4; ++m) {
            afh[m] = *(const short8*)&Ah[wr + m * 16 + fr][kg * 8];
            afl[m] = *(const short8*)&Al[wr + m * 16 + fr][kg * 8];
        }
#pragma unroll
        for (int n = 0; n < 4; ++n)
            bf_[n] = *(const short8*)&Bs[wc + n * 16 + fr][kg * 8];
#pragma unroll
        for (int m = 0; m < 4; ++m)
#pragma unroll
            for (int n = 0; n < 4; ++n) {
                acc[m][n] = MFMA(afh[m], bf_[n], acc[m][n]);
                acc[m][n] = MFMA(afl[m], bf_[n], acc[m][n]);
            }
    }
#pragma unroll
    for (int m = 0; m < 4; ++m)
#pragma unroll
        for (int n = 0; n < 4; ++n)
#pragma unroll
            for (int r = 0; r < 4; ++r) {
                int mm = mb + wr + m * 16 + kg * 4 + r;
                int vv = vb + wc + n * 16 + fr;
                __builtin_nontemporal_store(acc[m][n][r], &out[(size_t)mm * V_ + vv]);
            }
}

// ---------------- launcher ----------------

extern "C" void kernel_launch(void* const* d_in, const int* in_sizes, int n_in,
                              void* d_out, int out_size, void* d_ws, size_t ws_size,
                              hipStream_t stream) {
    (void)in_sizes; (void)n_in; (void)out_size; (void)ws_size;
    const float* enc    = (const float*)d_in[0];
    const float* mask   = (const float*)d_in[1];
    const int*   label  = (const int*)d_in[2];
    const float* emb_w  = (const float*)d_in[3];
    const float* W_ih   = (const float*)d_in[4];
    const float* b_ih   = (const float*)d_in[5];
    const float* W_hh   = (const float*)d_in[6];
    const float* b_hh   = (const float*)d_in[7];
    const float* proj_W = (const float*)d_in[8];
    const float* proj_b = (const float*)d_in[9];
    const float* emb0   = (const float*)d_in[10];
    const float* h0     = (const float*)d_in[11];
    const float* c0     = (const float*)d_in[12];
    float* out = (float*)d_out;

    char* w = (char*)d_ws;
    size_t o = 0;
    bf16* Wgh  = (bf16*)(w + o); o += (size_t)4096 * KX * 2;     // 21.0 MB
    bf16* Wgl  = (bf16*)(w + o); o += (size_t)4096 * KX * 2;     // 21.0 MB
    bf16* PWh  = (bf16*)(w + o); o += (size_t)512 * KP * 2;      // 2.1 MB
    bf16* PWl  = (bf16*)(w + o); o += (size_t)512 * KP * 2;      // 2.1 MB
    bf16* Eb   = (bf16*)(w + o); o += (size_t)V_ * 512 * 2;      // 32.8 MB
    float* bias= (float*)(w + o); o += 4096 * 4;
    bf16* Xh   = (bf16*)(w + o); o += (size_t)32 * KX * 2;
    bf16* Xl   = (bf16*)(w + o); o += (size_t)32 * KX * 2;
    bf16* Hh   = (bf16*)(w + o); o += (size_t)32 * 1024 * 2;
    bf16* Hl   = (bf16*)(w + o); o += (size_t)32 * 1024 * 2;
    bf16* Ph   = (bf16*)(w + o); o += (size_t)2048 * 512 * 2;    // 2.1 MB
    bf16* Pl   = (bf16*)(w + o); o += (size_t)2048 * 512 * 2;    // 2.1 MB
    float* hb  = (float*)(w + o); o += (size_t)32 * 1024 * 4;
    float* cb  = (float*)(w + o); o += (size_t)32 * 1024 * 4;
    float* pml = (float*)(w + o); o += (size_t)32 * NCH * 2 * 4;
    float* pctx= (float*)(w + o); o += (size_t)32 * NCH * 1024 * 4;  // 4.2 MB
    // total ~85 MB

    k_build_wg<<<4096, 256, 0, stream>>>(W_ih, W_hh, b_ih, b_hh, Wgh, Wgl, bias);
    k_cvt_split<<<1024, 256, 0, stream>>>(proj_W, PWh, PWl, (long)512 * KP);
    k_cvt<<<8192, 256, 0, stream>>>(emb_w, Eb, (long)V_ * 512);
    k_init<<<32, 256, 0, stream>>>(h0, c0, emb0, hb, cb, Hh, Hl, Xh, Xl);

    for (int t = 0; t <= T_; ++t) {
        k_att<<<32 + 32 * NCH, 256, 0, stream>>>(enc, mask, hb, Xh, Xl, Hh, Hl,
                                                 PWh, PWl, proj_b, emb_w, label,
                                                 Ph, Pl, pml, pctx, t);
        if (t < T_) {
            k_comb<<<32, 256, 0, stream>>>(pml, pctx, Hh, Hl, Xh, Xl);
            k_gates<<<256, 256, 0, stream>>>(Xh, Xl, Wgh, Wgl, bias, cb, hb, Hh, Hl);
        }
    }
    k_out<<<4000, 256, 0, stream>>>(Ph, Pl, Eb, out);
}

// Round 14
// 2822.488 us; speedup vs baseline: 4.8272x; 1.1813x over previous
//
#include <hip/hip_runtime.h>
#include <hip/hip_bf16.h>

// Decoder: attention + LSTMCell + proj + vocab scoring.
// B=32, S=512, T=64, DENC=DHID=1024, DEMB=512, V=32000.
// Precision: recurrent state f32; GEMMs split-bf16 (hi/lo, 3 MFMA chains).
// Structure (race-free): k_att [proj(t-1)+att partials] -> k_comb -> k_gates.
// R14: gates 512thr/8-way K-split (2 waves/SIMD); att 32-row chunks with
//      in-wave online rescale (NCH=16, half the blocks/partials);
//      k_out LDS pad 44 shorts (22-bank stride -> <=2-way conflicts).

#define B_   32
#define S_   512
#define T_   64
#define DENC 1024
#define DHID 1024
#define DEMB 512
#define V_   32000
#define KX   2560   // X row: [ctx 1024 | h 1024 | e 512]
#define KP   2048   // proj K: [ctx | h]
#define NCH  16     // attention s-chunks per batch (32 rows each)

using short8 = __attribute__((ext_vector_type(8))) short;
using f32x4  = __attribute__((ext_vector_type(4))) float;
typedef __hip_bfloat16 bf16;

__device__ __forceinline__ float sigmoidf_(float x) { return 1.0f / (1.0f + expf(-x)); }
__device__ __forceinline__ bf16 bhi(float x) { return __float2bfloat16(x); }
__device__ __forceinline__ bf16 blo(float x) {
    return __float2bfloat16(x - __bfloat162float(__float2bfloat16(x)));
}

#define MFMA(a, b, c) __builtin_amdgcn_mfma_f32_16x16x32_bf16((a), (b), (c), 0, 0, 0)
#define DOT4(a, b) fmaf((a).x, (b).x, fmaf((a).y, (b).y, fmaf((a).z, (b).z, (a).w * (b).w)))

// ---------------- setup kernels ----------------

__global__ void k_build_wg(const float* __restrict__ W_ih, const float* __restrict__ W_hh,
                           const float* __restrict__ b_ih, const float* __restrict__ b_hh,
                           bf16* __restrict__ Wh, bf16* __restrict__ Wl, float* __restrict__ bias) {
    int jp = blockIdx.x;            // 0..4095, j' = d*4 + gate
    int g = jp & 3, d = jp >> 2;
    int j = g * 1024 + d;           // source row (torch gate order i,f,g,o)
    const float* wi = W_ih + (size_t)j * 1536;
    const float* wh = W_hh + (size_t)j * 1024;
    bf16* dh = Wh + (size_t)jp * KX;
    bf16* dl = Wl + (size_t)jp * KX;
    for (int i = threadIdx.x; i < 1024; i += 256) { float v = wi[i];      dh[i] = bhi(v);        dl[i] = blo(v); }
    for (int i = threadIdx.x; i < 1024; i += 256) { float v = wh[i];      dh[1024+i] = bhi(v);   dl[1024+i] = blo(v); }
    for (int i = threadIdx.x; i < 512;  i += 256) { float v = wi[1024+i]; dh[2048+i] = bhi(v);   dl[2048+i] = blo(v); }
    if (threadIdx.x == 0) bias[jp] = b_ih[j] + b_hh[j];
}

__global__ void k_cvt(const float* __restrict__ src, bf16* __restrict__ dst, long n) {
    long i = (long)blockIdx.x * blockDim.x + threadIdx.x;
    long stride = (long)gridDim.x * blockDim.x;
    for (; i < n; i += stride) dst[i] = __float2bfloat16(src[i]);
}

__global__ void k_cvt_split(const float* __restrict__ src, bf16* __restrict__ dh,
                            bf16* __restrict__ dl, long n) {
    long i = (long)blockIdx.x * blockDim.x + threadIdx.x;
    long stride = (long)gridDim.x * blockDim.x;
    for (; i < n; i += stride) { float v = src[i]; dh[i] = bhi(v); dl[i] = blo(v); }
}

__global__ void k_init(const float* __restrict__ h0, const float* __restrict__ c0,
                       const float* __restrict__ emb0,
                       float* __restrict__ h, float* __restrict__ c,
                       bf16* __restrict__ Hh, bf16* __restrict__ Hl,
                       bf16* __restrict__ Xh_, bf16* __restrict__ Xl_) {
    int b = blockIdx.x;   // 32 blocks
    for (int d = threadIdx.x; d < 1024; d += 256) {
        float v = h0[d];
        h[b * 1024 + d] = v;
        c[b * 1024 + d] = c0[d];
        Hh[b * 1024 + d] = bhi(v);
        Hl[b * 1024 + d] = blo(v);
    }
    for (int d = threadIdx.x; d < 512; d += 256) {
        float v = emb0[d];
        Xh_[(size_t)b * KX + 2048 + d] = bhi(v);
        Xl_[(size_t)b * KX + 2048 + d] = blo(v);
    }
}

// ---------------- per-step kernel 1: proj(t-1) + attention partials(t) ----------------

// blocks 0..31:   proj for step t-1 (if t>0) + e-gather into X.e.
// blocks 32..543: attention partials for step t: (b, chunk) = 32 s-rows; each
//                 wave does 8 rows as 2 online-rescaled batches of 4.
__global__ __launch_bounds__(256) void k_att(
    const float* __restrict__ enc, const float* __restrict__ mask,
    const float* __restrict__ h,
    bf16* __restrict__ Xh_, bf16* __restrict__ Xl_,
    const bf16* __restrict__ Hh, const bf16* __restrict__ Hl,
    const bf16* __restrict__ PWh, const bf16* __restrict__ PWl,
    const float* __restrict__ pb, const float* __restrict__ emb_w,
    const int* __restrict__ label,
    bf16* __restrict__ Ph, bf16* __restrict__ Pl,
    float* __restrict__ pml, float* __restrict__ pctx, int t)
{
    __shared__ float pr[4][32][17];
    __shared__ float lctx[4][1024];
    __shared__ float lm[4], ll[4];

    int bid = blockIdx.x;
    int tid = threadIdx.x, wave = tid >> 6, lane = tid & 63;

    if (bid < 32) {
        // ---------- proj for step t-1: p = [ctx_{t-1} | h_t] @ PW^T + pb ----------
        if (t == 0) return;
        int tp = t - 1;
        int nb = bid * 16;
        int ncol = nb + (lane & 15);
        int kc = wave * 512;
        const short* ah;
        const short* al;
        size_t astr, aoff;
        if (wave < 2) { ah = (const short*)Xh_; al = (const short*)Xl_; astr = KX;   aoff = kc; }
        else          { ah = (const short*)Hh;  al = (const short*)Hl;  astr = 1024; aoff = kc - 1024; }
        const short* wrh = (const short*)PWh + (size_t)ncol * KP + kc + (lane >> 4) * 8;
        const short* wrl = (const short*)PWl + (size_t)ncol * KP + kc + (lane >> 4) * 8;
        size_t arow0 = (size_t)(lane & 15) * astr + aoff + (lane >> 4) * 8;
        size_t arow1 = (size_t)((lane & 15) + 16) * astr + aoff + (lane >> 4) * 8;
        f32x4 acc0 = {0, 0, 0, 0}, acc1 = {0, 0, 0, 0};
#pragma unroll 4
        for (int kk = 0; kk < 16; ++kk) {
            int ko = kk * 32;
            short8 a0h = *(const short8*)(ah + arow0 + ko);
            short8 a1h = *(const short8*)(ah + arow1 + ko);
            short8 a0l = *(const short8*)(al + arow0 + ko);
            short8 a1l = *(const short8*)(al + arow1 + ko);
            short8 bh = *(const short8*)(wrh + ko);
            short8 bl = *(const short8*)(wrl + ko);
            acc0 = MFMA(a0h, bh, acc0); acc1 = MFMA(a1h, bh, acc1);
            acc0 = MFMA(a0h, bl, acc0); acc1 = MFMA(a1h, bl, acc1);
            acc0 = MFMA(a0l, bh, acc0); acc1 = MFMA(a1l, bh, acc1);
        }
#pragma unroll
        for (int r = 0; r < 4; ++r) {
            pr[wave][(lane >> 4) * 4 + r][lane & 15]      = acc0[r];
            pr[wave][16 + (lane >> 4) * 4 + r][lane & 15] = acc1[r];
        }
        __syncthreads();
        for (int p = tid; p < 512; p += 256) {
            int bb = p >> 4, col = p & 15;
            float v = pr[0][bb][col] + pr[1][bb][col] + pr[2][bb][col] + pr[3][bb][col]
                      + pb[nb + col];
            size_t mi = (size_t)(bb * 64 + tp) * 512 + nb + col;
            Ph[mi] = bhi(v);
            Pl[mi] = blo(v);
        }
        int b = bid;
        int wd = label[b * 64 + tp];
        wd = wd < 0 ? 0 : (wd > V_ - 1 ? V_ - 1 : wd);
        const float* ew = emb_w + (size_t)wd * 512;
        for (int d = tid; d < 512; d += 256) {
            float v = ew[d];
            Xh_[(size_t)b * KX + 2048 + d] = bhi(v);
            Xl_[(size_t)b * KX + 2048 + d] = blo(v);
        }
        return;
    }

    // ---------- attention partials for step t ----------
    if (t >= T_) return;
    int ab = bid - 32;
    int b = ab >> 4, ch = ab & (NCH - 1);      // chunk = 32 s-rows; wave does 8

    float4 hreg[4];
    const float4* h4p = (const float4*)(h + b * 1024);
#pragma unroll
    for (int j = 0; j < 4; ++j) hreg[j] = h4p[j * 64 + lane];

    const float* encb = enc + (size_t)b * S_ * DENC;
    int srow0 = ch * 32 + wave * 8;

    float m = -3.0e38f, l = 0.f;
    float4 c0 = {0,0,0,0}, c1 = {0,0,0,0}, c2 = {0,0,0,0}, c3 = {0,0,0,0};
#pragma unroll
    for (int half = 0; half < 2; ++half) {
        int sr = srow0 + half * 4;
        const float4* r0 = (const float4*)(encb + (size_t)(sr + 0) * DENC);
        const float4* r1 = (const float4*)(encb + (size_t)(sr + 1) * DENC);
        const float4* r2 = (const float4*)(encb + (size_t)(sr + 2) * DENC);
        const float4* r3 = (const float4*)(encb + (size_t)(sr + 3) * DENC);
        float4 e00 = r0[lane], e01 = r0[64+lane], e02 = r0[128+lane], e03 = r0[192+lane];
        float4 e10 = r1[lane], e11 = r1[64+lane], e12 = r1[128+lane], e13 = r1[192+lane];
        float4 e20 = r2[lane], e21 = r2[64+lane], e22 = r2[128+lane], e23 = r2[192+lane];
        float4 e30 = r3[lane], e31 = r3[64+lane], e32 = r3[128+lane], e33 = r3[192+lane];

        float d0 = DOT4(e00,hreg[0]) + DOT4(e01,hreg[1]) + DOT4(e02,hreg[2]) + DOT4(e03,hreg[3]);
        float d1 = DOT4(e10,hreg[0]) + DOT4(e11,hreg[1]) + DOT4(e12,hreg[2]) + DOT4(e13,hreg[3]);
        float d2 = DOT4(e20,hreg[0]) + DOT4(e21,hreg[1]) + DOT4(e22,hreg[2]) + DOT4(e23,hreg[3]);
        float d3 = DOT4(e30,hreg[0]) + DOT4(e31,hreg[1]) + DOT4(e32,hreg[2]) + DOT4(e33,hreg[3]);
#pragma unroll
        for (int off = 32; off; off >>= 1) {
            d0 += __shfl_xor(d0, off, 64);
            d1 += __shfl_xor(d1, off, 64);
            d2 += __shfl_xor(d2, off, 64);
            d3 += __shfl_xor(d3, off, 64);
        }
        float sc0 = d0 - (1.0f - mask[b * S_ + sr + 0]) * 1e20f;
        float sc1 = d1 - (1.0f - mask[b * S_ + sr + 1]) * 1e20f;
        float sc2 = d2 - (1.0f - mask[b * S_ + sr + 2]) * 1e20f;
        float sc3 = d3 - (1.0f - mask[b * S_ + sr + 3]) * 1e20f;
        float mw = fmaxf(fmaxf(sc0, sc1), fmaxf(sc2, sc3));
        float mn = fmaxf(m, mw);
        float f = expf(m - mn);        // rescale old accumulators (0 on first half)
        float g = expf(mw - mn);       // scale new batch
        float w0 = expf(sc0 - mw) * g, w1 = expf(sc1 - mw) * g;
        float w2 = expf(sc2 - mw) * g, w3 = expf(sc3 - mw) * g;
        l = l * f + (w0 + w1 + w2 + w3);
        c0.x = c0.x * f + w0*e00.x + w1*e10.x + w2*e20.x + w3*e30.x;
        c0.y = c0.y * f + w0*e00.y + w1*e10.y + w2*e20.y + w3*e30.y;
        c0.z = c0.z * f + w0*e00.z + w1*e10.z + w2*e20.z + w3*e30.z;
        c0.w = c0.w * f + w0*e00.w + w1*e10.w + w2*e20.w + w3*e30.w;
        c1.x = c1.x * f + w0*e01.x + w1*e11.x + w2*e21.x + w3*e31.x;
        c1.y = c1.y * f + w0*e01.y + w1*e11.y + w2*e21.y + w3*e31.y;
        c1.z = c1.z * f + w0*e01.z + w1*e11.z + w2*e21.z + w3*e31.z;
        c1.w = c1.w * f + w0*e01.w + w1*e11.w + w2*e21.w + w3*e31.w;
        c2.x = c2.x * f + w0*e02.x + w1*e12.x + w2*e22.x + w3*e32.x;
        c2.y = c2.y * f + w0*e02.y + w1*e12.y + w2*e22.y + w3*e32.y;
        c2.z = c2.z * f + w0*e02.z + w1*e12.z + w2*e22.z + w3*e32.z;
        c2.w = c2.w * f + w0*e02.w + w1*e12.w + w2*e22.w + w3*e32.w;
        c3.x = c3.x * f + w0*e03.x + w1*e13.x + w2*e23.x + w3*e33.x;
        c3.y = c3.y * f + w0*e03.y + w1*e13.y + w2*e23.y + w3*e33.y;
        c3.z = c3.z * f + w0*e03.z + w1*e13.z + w2*e23.z + w3*e33.z;
        c3.w = c3.w * f + w0*e03.w + w1*e13.w + w2*e23.w + w3*e33.w;
        m = mn;
    }

    ((float4*)lctx[wave])[0 * 64 + lane] = c0;
    ((float4*)lctx[wave])[1 * 64 + lane] = c1;
    ((float4*)lctx[wave])[2 * 64 + lane] = c2;
    ((float4*)lctx[wave])[3 * 64 + lane] = c3;
    if (lane == 0) { lm[wave] = m; ll[wave] = l; }
    __syncthreads();

    float mb_ = fmaxf(fmaxf(lm[0], lm[1]), fmaxf(lm[2], lm[3]));
    float q0 = expf(lm[0] - mb_), q1 = expf(lm[1] - mb_);
    float q2 = expf(lm[2] - mb_), q3 = expf(lm[3] - mb_);
    float lb = ll[0] * q0 + ll[1] * q1 + ll[2] * q2 + ll[3] * q3;
    float4 a0 = ((float4*)lctx[0])[tid], a1 = ((float4*)lctx[1])[tid];
    float4 a2 = ((float4*)lctx[2])[tid], a3 = ((float4*)lctx[3])[tid];
    float4 v;
    v.x = a0.x * q0 + a1.x * q1 + a2.x * q2 + a3.x * q3;
    v.y = a0.y * q0 + a1.y * q1 + a2.y * q2 + a3.y * q3;
    v.z = a0.z * q0 + a1.z * q1 + a2.z * q2 + a3.z * q3;
    v.w = a0.w * q0 + a1.w * q1 + a2.w * q2 + a3.w * q3;
    int pi = b * NCH + ch;
    ((float4*)(pctx + (size_t)pi * 1024))[tid] = v;
    if (tid == 0) { pml[pi * 2] = mb_; pml[pi * 2 + 1] = lb; }
}

// ---------------- per-step kernel 2: combine partials -> X.ctx, copy H -> X.h ----------------

__global__ __launch_bounds__(256) void k_comb(const float* __restrict__ pml,
                                              const float* __restrict__ pctx,
                                              const bf16* __restrict__ Hh,
                                              const bf16* __restrict__ Hl,
                                              bf16* __restrict__ Xh_, bf16* __restrict__ Xl_) {
    __shared__ float sml[NCH * 2];
    __shared__ float wch[NCH];
    int b = blockIdx.x, tid = threadIdx.x;
    if (tid < NCH * 2) sml[tid] = pml[b * NCH * 2 + tid];
    __syncthreads();
    float mf = -3.0e38f;
#pragma unroll
    for (int c = 0; c < NCH; ++c) mf = fmaxf(mf, sml[2 * c]);
    float lt = 0.f;
#pragma unroll
    for (int c = 0; c < NCH; ++c) lt += sml[2 * c + 1] * expf(sml[2 * c] - mf);
    if (tid < NCH) wch[tid] = expf(sml[2 * tid] - mf);
    __syncthreads();
    float inv = 1.0f / lt;
    const float4* base = (const float4*)(pctx + (size_t)b * NCH * 1024) + tid;
    float4 sacc = {0, 0, 0, 0};
#pragma unroll 8
    for (int c = 0; c < NCH; ++c) {
        float wc = wch[c];
        float4 p = base[c * 256];
        sacc.x = fmaf(wc, p.x, sacc.x); sacc.y = fmaf(wc, p.y, sacc.y);
        sacc.z = fmaf(wc, p.z, sacc.z); sacc.w = fmaf(wc, p.w, sacc.w);
    }
    sacc.x *= inv; sacc.y *= inv; sacc.z *= inv; sacc.w *= inv;
    size_t xi = (size_t)b * KX + tid * 4;
    Xh_[xi + 0] = bhi(sacc.x); Xl_[xi + 0] = blo(sacc.x);
    Xh_[xi + 1] = bhi(sacc.y); Xl_[xi + 1] = blo(sacc.y);
    Xh_[xi + 2] = bhi(sacc.z); Xl_[xi + 2] = blo(sacc.z);
    Xh_[xi + 3] = bhi(sacc.w); Xl_[xi + 3] = blo(sacc.w);
    ((unsigned long long*)(Xh_ + (size_t)b * KX + 1024))[tid] =
        ((const unsigned long long*)(Hh + (size_t)b * 1024))[tid];
    ((unsigned long long*)(Xl_ + (size_t)b * KX + 1024))[tid] =
        ((const unsigned long long*)(Hl + (size_t)b * 1024))[tid];
}

// ---------------- per-step kernel 3: gates ----------------

// gates = X[32x2560] @ Wg^T[4096x2560] + bias (split-bf16, 3 chains), fused LSTM
// pointwise. 256 blocks x 512 thr: block = 16 cols; 8 waves = 8-way K-split
// (320 each, 10 iters) -> 2 waves/SIMD for latency hiding. LDS reduce.
// Writes cb/hb/H only (race-free).
__global__ __launch_bounds__(512) void k_gates(
    const bf16* __restrict__ Xh_, const bf16* __restrict__ Xl_,
    const bf16* __restrict__ Wh_, const bf16* __restrict__ Wl_,
    const float* __restrict__ bias,
    float* __restrict__ c, float* __restrict__ h,
    bf16* __restrict__ Hh, bf16* __restrict__ Hl)
{
    __shared__ float pr[8][32][17];
    int jb = blockIdx.x * 16;
    int tid = threadIdx.x, wave = tid >> 6, lane = tid & 63;
    int jcol = jb + (lane & 15);
    int kc = wave * 320 + (lane >> 4) * 8;
    const short* xhp = (const short*)Xh_ + kc;
    const short* xlp = (const short*)Xl_ + kc;
    const short* wrh = (const short*)Wh_ + (size_t)jcol * KX + kc;
    const short* wrl = (const short*)Wl_ + (size_t)jcol * KX + kc;
    size_t arow0 = (size_t)(lane & 15) * KX;
    size_t arow1 = (size_t)((lane & 15) + 16) * KX;
    f32x4 acc0 = {0, 0, 0, 0}, acc1 = {0, 0, 0, 0};
#pragma unroll 5
    for (int kk = 0; kk < 10; ++kk) {
        int ko = kk * 32;
        short8 a0h = *(const short8*)(xhp + arow0 + ko);
        short8 a1h = *(const short8*)(xhp + arow1 + ko);
        short8 a0l = *(const short8*)(xlp + arow0 + ko);
        short8 a1l = *(const short8*)(xlp + arow1 + ko);
        short8 bh = *(const short8*)(wrh + ko);
        short8 bl = *(const short8*)(wrl + ko);
        acc0 = MFMA(a0h, bh, acc0); acc1 = MFMA(a1h, bh, acc1);
        acc0 = MFMA(a0h, bl, acc0); acc1 = MFMA(a1h, bl, acc1);
        acc0 = MFMA(a0l, bh, acc0); acc1 = MFMA(a1l, bh, acc1);
    }
#pragma unroll
    for (int r = 0; r < 4; ++r) {
        pr[wave][(lane >> 4) * 4 + r][lane & 15]      = acc0[r];
        pr[wave][16 + (lane >> 4) * 4 + r][lane & 15] = acc1[r];
    }
    __syncthreads();
    if (tid < 128) {
        int bb = tid & 31, dd = tid >> 5;
        int cb = dd * 4;
        float g0 = 0.f, g1 = 0.f, g2 = 0.f, g3 = 0.f;
#pragma unroll
        for (int q = 0; q < 8; ++q) {
            g0 += pr[q][bb][cb + 0];
            g1 += pr[q][bb][cb + 1];
            g2 += pr[q][bb][cb + 2];
            g3 += pr[q][bb][cb + 3];
        }
        float gi = g0 + bias[jb + cb + 0];
        float gf = g1 + bias[jb + cb + 1];
        float gg = g2 + bias[jb + cb + 2];
        float go = g3 + bias[jb + cb + 3];
        int d = (jb >> 2) + dd;
        float cv = c[bb * 1024 + d];
        float cn = sigmoidf_(gf) * cv + sigmoidf_(gi) * tanhf(gg);
        float hn = sigmoidf_(go) * tanhf(cn);
        c[bb * 1024 + d] = cn;
        h[bb * 1024 + d] = hn;
        Hh[bb * 1024 + d] = bhi(hn);
        Hl[bb * 1024 + d] = blo(hn);
    }
}

// ---------------- final vocab GEMM (128x128 tile) ----------------

// OUT[m][v] = P[m][:] . emb_w[v][:]. P split hi/lo share one acc chain.
// Tile 128x128, BK=32, 16 K-steps. LDS [128][44] (88B stride = 22 banks,
// gcd(22,32)=2 -> <=2-way read conflicts, free). 33.8KB LDS, 4 blocks/CU.
// Grid 4000 m-inner.
__global__ __launch_bounds__(256) void k_out(const bf16* __restrict__ Ph,
                                             const bf16* __restrict__ Pl,
                                             const bf16* __restrict__ Eb,
                                             float* __restrict__ out) {
    int bid = blockIdx.x;
    int vb = (bid >> 4) * 128;
    int mb = (bid & 15) * 128;

    __shared__ __align__(16) short Ah[128][44];
    __shared__ __align__(16) short Al[128][44];
    __shared__ __align__(16) short Bs[128][44];

    int tid = threadIdx.x, wave = tid >> 6, lane = tid & 63;
    int wr = (wave >> 1) * 64, wc = (wave & 1) * 64;
    int fr = lane & 15, kg = lane >> 4;

    f32x4 acc[4][4];
#pragma unroll
    for (int m = 0; m < 4; ++m)
#pragma unroll
        for (int n = 0; n < 4; ++n) acc[m][n] = (f32x4){0, 0, 0, 0};

    const short* Pp = (const short*)Ph;
    const short* Plp = (const short*)Pl;
    const short* Ep = (const short*)Eb;

    for (int ks = 0; ks < 16; ++ks) {
        int k0 = ks * 32;
        __syncthreads();
#pragma unroll
        for (int j = 0; j < 2; ++j) {
            int cch = tid + j * 256;
            int r = cch >> 2, cg = (cch & 3) * 8;
            *(short8*)&Ah[r][cg] = *(const short8*)(Pp  + (size_t)(mb + r) * 512 + k0 + cg);
            *(short8*)&Al[r][cg] = *(const short8*)(Plp + (size_t)(mb + r) * 512 + k0 + cg);
            *(short8*)&Bs[r][cg] = *(const short8*)(Ep  + (size_t)(vb + r) * 512 + k0 + cg);
        }
        __syncthreads();
        short8 afh[4], afl[4], bf_[4];
#pragma unroll
        for (int m = 0; m < 4; ++m) {
            afh[m] = *(const short8*)&Ah[wr + m * 16 + fr][kg * 8];
            afl[m] = *(const short8*)&Al[wr + m * 16 + fr][kg * 8];
        }
#pragma unroll
        for (int n = 0; n < 4; ++n)
            bf_[n] = *(const short8*)&Bs[wc + n * 16 + fr][kg * 8];
#pragma unroll
        for (int m = 0; m < 4; ++m)
#pragma unroll
            for (int n = 0; n < 4; ++n) {
                acc[m][n] = MFMA(afh[m], bf_[n], acc[m][n]);
                acc[m][n] = MFMA(afl[m], bf_[n], acc[m][n]);
            }
    }
#pragma unroll
    for (int m = 0; m < 4; ++m)
#pragma unroll
        for (int n = 0; n < 4; ++n)
#pragma unroll
            for (int r = 0; r < 4; ++r) {
                int mm = mb + wr + m * 16 + kg * 4 + r;
                int vv = vb + wc + n * 16 + fr;
                __builtin_nontemporal_store(acc[m][n][r], &out[(size_t)mm * V_ + vv]);
            }
}

// ---------------- launcher ----------------

extern "C" void kernel_launch(void* const* d_in, const int* in_sizes, int n_in,
                              void* d_out, int out_size, void* d_ws, size_t ws_size,
                              hipStream_t stream) {
    (void)in_sizes; (void)n_in; (void)out_size; (void)ws_size;
    const float* enc    = (const float*)d_in[0];
    const float* mask   = (const float*)d_in[1];
    const int*   label  = (const int*)d_in[2];
    const float* emb_w  = (const float*)d_in[3];
    const float* W_ih   = (const float*)d_in[4];
    const float* b_ih   = (const float*)d_in[5];
    const float* W_hh   = (const float*)d_in[6];
    const float* b_hh   = (const float*)d_in[7];
    const float* proj_W = (const float*)d_in[8];
    const float* proj_b = (const float*)d_in[9];
    const float* emb0   = (const float*)d_in[10];
    const float* h0     = (const float*)d_in[11];
    const float* c0     = (const float*)d_in[12];
    float* out = (float*)d_out;

    char* w = (char*)d_ws;
    size_t o = 0;
    bf16* Wgh  = (bf16*)(w + o); o += (size_t)4096 * KX * 2;     // 21.0 MB
    bf16* Wgl  = (bf16*)(w + o); o += (size_t)4096 * KX * 2;     // 21.0 MB
    bf16* PWh  = (bf16*)(w + o); o += (size_t)512 * KP * 2;      // 2.1 MB
    bf16* PWl  = (bf16*)(w + o); o += (size_t)512 * KP * 2;      // 2.1 MB
    bf16* Eb   = (bf16*)(w + o); o += (size_t)V_ * 512 * 2;      // 32.8 MB
    float* bias= (float*)(w + o); o += 4096 * 4;
    bf16* Xh   = (bf16*)(w + o); o += (size_t)32 * KX * 2;
    bf16* Xl   = (bf16*)(w + o); o += (size_t)32 * KX * 2;
    bf16* Hh   = (bf16*)(w + o); o += (size_t)32 * 1024 * 2;
    bf16* Hl   = (bf16*)(w + o); o += (size_t)32 * 1024 * 2;
    bf16* Ph   = (bf16*)(w + o); o += (size_t)2048 * 512 * 2;    // 2.1 MB
    bf16* Pl   = (bf16*)(w + o); o += (size_t)2048 * 512 * 2;    // 2.1 MB
    float* hb  = (float*)(w + o); o += (size_t)32 * 1024 * 4;
    float* cb  = (float*)(w + o); o += (size_t)32 * 1024 * 4;
    float* pml = (float*)(w + o); o += (size_t)32 * NCH * 2 * 4;
    float* pctx= (float*)(w + o); o += (size_t)32 * NCH * 1024 * 4;  // 2.1 MB
    // total ~83 MB

    k_build_wg<<<4096, 256, 0, stream>>>(W_ih, W_hh, b_ih, b_hh, Wgh, Wgl, bias);
    k_cvt_split<<<1024, 256, 0, stream>>>(proj_W, PWh, PWl, (long)512 * KP);
    k_cvt<<<8192, 256, 0, stream>>>(emb_w, Eb, (long)V_ * 512);
    k_init<<<32, 256, 0, stream>>>(h0, c0, emb0, hb, cb, Hh, Hl, Xh, Xl);

    for (int t = 0; t <= T_; ++t) {
        k_att<<<32 + 32 * NCH, 256, 0, stream>>>(enc, mask, hb, Xh, Xl, Hh, Hl,
                                                 PWh, PWl, proj_b, emb_w, label,
                                                 Ph, Pl, pml, pctx, t);
        if (t < T_) {
            k_comb<<<32, 256, 0, stream>>>(pml, pctx, Hh, Hl, Xh, Xl);
            k_gates<<<256, 512, 0, stream>>>(Xh, Xl, Wgh, Wgl, bias, cb, hb, Hh, Hl);
        }
    }
    k_out<<<4000, 256, 0, stream>>>(Ph, Pl, Eb, out);
}